// Round 10
// baseline (201.226 us; speedup 1.0000x reference)
//
#include <hip/hip_runtime.h>

// Problem constants (from reference setup_inputs)
constexpr int B = 16;
constexpr int D = 256;
constexpr int K = 18;
constexpr int KH = 9;           // half-K (lane-pair split)
constexpr int SZ = 128;
constexpr int S = SZ * SZ;      // 16384 positions per plane
constexpr int N = S / 2;        // 8192 sampled positions
constexpr int PB = 512;         // positions per block

// ---------------------------------------------------------------------------
// Prep (identical to passing round 5): blocks 0..31 scatter mask ones (mask
// pre-zeroed by memset); blocks 32..103 compute p2[b*K+k] = ||proto||^2 fp64.
// ---------------------------------------------------------------------------
__global__ __launch_bounds__(256) void prep2_kernel(
    const float* __restrict__ proto,
    const int* __restrict__ idx,
    unsigned char* __restrict__ mask,
    double* __restrict__ p2) {
  const int blk = blockIdx.x;
  if (blk < 32) {
    mask[idx[blk * 256 + threadIdx.x]] = 1;   // indices are a permutation
  } else {
    const int row  = (blk - 32) * 4 + (threadIdx.x >> 6);  // 0..287 = b*K+k
    const int lane = threadIdx.x & 63;
    const float4 v = *(const float4*)(proto + (size_t)row * D + lane * 4);
    double s = (double)v.x * (double)v.x + (double)v.y * (double)v.y
             + (double)v.z * (double)v.z + (double)v.w * (double)v.w;
#pragma unroll
    for (int off = 1; off < 64; off <<= 1)
      s += __shfl_xor(s, off, 64);
    if (lane == 0) p2[row] = s;
  }
}

// ---------------------------------------------------------------------------
// Fused argmin + output. Block = 256 threads (4 waves), (b, 512-pos chunk).
// Grid 512 = 2 blocks/CU (LDS 55 KiB) = 8 waves/CU.
//  dot:   lane-pair K-split. pair = lane>>1 owns 4 consecutive positions
//         (pos0 + 4*pair + 0..3); kh = lane&1 picks k in [9*kh, 9*kh+9).
//         Both pair lanes load the SAME float4 of f (coalescer dedupes ->
//         bytes unchanged); proto via LDS fp64 reads, 9 per d per lane
//         (2 unique addrs/wave, conflict-free). acc[4][9] fp64 = 72 VGPR --
//         half of r9's 144, the level that compiled spill-free in r5.
//  argmin: per-half strict < over ascending k, then one shfl_xor(1) combine;
//         bLow <= bHigh -> kLow  ==  numpy first-min over k=0..17 exactly.
//         Per-(pos,k) accumulation is d-ascending 0..255 -> decisions
//         bit-identical to rounds 1-5 (absmax 0.0 each time).
//  output: fused (r8 proved the re-read is L3-absorbed: FETCH ~= input once).
//         d DESCENDING (L3 tail), select vs fp32 LDS proto, float2 stores.
// ---------------------------------------------------------------------------
__global__ __launch_bounds__(256, 2) void fused_kernel(
    const float* __restrict__ assp,
    const float* __restrict__ proto,
    const double* __restrict__ p2,
    const unsigned char* __restrict__ mask,
    float* __restrict__ out) {
  __shared__ double spd[D][K];          // 36 KiB, dot phase
  __shared__ float  spf[D][K];          // 18 KiB, output phase
  __shared__ unsigned char skst[PB];    // winning k per position

  const int b     = blockIdx.x & 15;    // batches spread across XCDs
  const int chunk = blockIdx.x >> 4;    // 0..31
  const int bpos0 = chunk * PB;
  const int tid   = threadIdx.x;

  const float* pbr = proto + (size_t)b * K * D;
  for (int i = tid; i < K * D; i += 256) {
    const int k = i >> 8, d = i & 255;
    const float v = pbr[i];
    spd[d][k] = (double)v;
    spf[d][k] = v;
  }
  __syncthreads();

  // ---- dot phase ----
  const int lane = tid & 63;
  const int wv   = tid >> 6;
  const int kh   = lane & 1;            // 0: k=0..8, 1: k=9..17
  const int pair = lane >> 1;           // 0..31
  const int lpos = wv * 128 + pair * 4; // block-local position of this pair
  const float* fin = assp + (size_t)b * D * S + bpos0 + lpos;

  double acc[4][KH];
#pragma unroll
  for (int jp = 0; jp < 4; ++jp)
#pragma unroll
    for (int j = 0; j < KH; ++j) acc[jp][j] = 0.0;

  for (int d0 = 0; d0 < D; d0 += 8) {
    float4 fv[8];
#pragma unroll
    for (int jd = 0; jd < 8; ++jd)                     // 8 loads in flight
      fv[jd] = *(const float4*)(fin + (size_t)(d0 + jd) * S);
#pragma unroll
    for (int jd = 0; jd < 8; ++jd) {
      const double f0 = (double)fv[jd].x;
      const double f1 = (double)fv[jd].y;
      const double f2 = (double)fv[jd].z;
      const double f3 = (double)fv[jd].w;
      const double* pr = &spd[d0 + jd][kh * KH];       // 9 doubles, my half
#pragma unroll
      for (int j = 0; j < KH; ++j) {
        const double pk = pr[j];
        acc[0][j] += f0 * pk;
        acc[1][j] += f1 * pk;
        acc[2][j] += f2 * pk;
        acc[3][j] += f3 * pk;
      }
    }
  }

  // ---- per-position argmin: own half, then cross-pair combine ----
  const double* p2h = p2 + (size_t)b * K + kh * KH;    // uniform-ish s_load
  int kst[4];
#pragma unroll
  for (int jp = 0; jp < 4; ++jp) {
    double bb = 1e300;
    int bj = 0;
#pragma unroll
    for (int j = 0; j < KH; ++j) {
      const double d2 = p2h[j] - 2.0 * acc[jp][j];
      if (d2 < bb) { bb = d2; bj = j; }    // strict <, ascending j
    }
    const int myk = kh * KH + bj;
    const double ob = __shfl_xor(bb, 1, 64);   // partner's half-best
    const int    ok = __shfl_xor(myk, 1, 64);
    const double bLow  = kh ? ob  : bb;
    const int    kLow  = kh ? ok  : myk;
    const double bHigh = kh ? bb  : ob;
    const int    kHigh = kh ? myk : ok;
    kst[jp] = (bLow <= bHigh) ? kLow : kHigh;  // ties -> lower k = first-min
  }

  if (kh == 0) {
    uchar4 kk;
    kk.x = (unsigned char)kst[0];
    kk.y = (unsigned char)kst[1];
    kk.z = (unsigned char)kst[2];
    kk.w = (unsigned char)kst[3];
    *(uchar4*)&skst[lpos] = kk;
  }
  __syncthreads();

  // ---- output phase: 2 positions/thread, d descending (L3 tail) ----
  const int p = 2 * tid;                       // block-local
  const uchar2 kk2 = *(const uchar2*)&skst[p];
  const uchar2 m   = *(const uchar2*)(mask + bpos0 + p);
  const float* fin2 = assp + (size_t)b * D * S + bpos0 + p;
  float*       op   = out  + (size_t)b * D * S + bpos0 + p;
  const int k0 = kk2.x, k1 = kk2.y;

  for (int d0 = D - 8; d0 >= 0; d0 -= 8) {
    float2 fa[8];
#pragma unroll
    for (int jd = 0; jd < 8; ++jd)
      fa[jd] = *(const float2*)(fin2 + (size_t)(d0 + jd) * S);
#pragma unroll
    for (int jd = 0; jd < 8; ++jd) {
      const int d = d0 + jd;
      float2 o;
      o.x = m.x ? spf[d][k0] : fa[jd].x;
      o.y = m.y ? spf[d][k1] : fa[jd].y;
      *(float2*)(op + (size_t)d * S) = o;
    }
  }
}

extern "C" void kernel_launch(void* const* d_in, const int* in_sizes, int n_in,
                              void* d_out, int out_size, void* d_ws, size_t ws_size,
                              hipStream_t stream) {
  const float* assp  = (const float*)d_in[0];
  const float* proto = (const float*)d_in[1];
  const int*   idx   = (const int*)d_in[2];
  float* out = (float*)d_out;

  // ws layout: [mask: S bytes][p2: B*K doubles]
  unsigned char* mask = (unsigned char*)d_ws;
  double*        p2   = (double*)((char*)d_ws + S);

  hipMemsetAsync(mask, 0, S, stream);   // 16 KiB
  prep2_kernel<<<104, 256, 0, stream>>>(proto, idx, mask, p2);
  fused_kernel<<<B * (S / PB), 256, 0, stream>>>(assp, proto, p2, mask, out);
}